// Round 5
// baseline (202.887 us; speedup 1.0000x reference)
//
#include <hip/hip_runtime.h>
#include <stdint.h>

#define DIMC 256
#define RTOT 1024
#define NE 64
#define NSLOT 1024
#define RC 256     // r-columns per block (grid.x = 4)
#define TILE 32    // max slots per pass
#define DT 32      // weight rows per staged tile
#define NT 16      // 8 w1 tiles + 8 w2 tiles
#define HMAX 16    // max slots per slot-half

typedef const __attribute__((address_space(1))) void* gptr_t;
typedef __attribute__((address_space(3))) void* lptr_t;

// ---------------- bucket slots by expert ----------------
__global__ __launch_bounds__(1024) void bucket_kernel(
    const int* __restrict__ idx, int* __restrict__ count,
    int* __restrict__ start, int* __restrict__ list) {
  __shared__ int cnt[NE];
  __shared__ int offs[NE];
  __shared__ int cur[NE];
  int t = threadIdx.x;
  if (t < NE) cnt[t] = 0;
  __syncthreads();
  int e = idx[t] & (NE - 1);
  atomicAdd(&cnt[e], 1);
  __syncthreads();
  if (t == 0) {
    int acc = 0;
    for (int i = 0; i < NE; ++i) { offs[i] = acc; cur[i] = acc; acc += cnt[i]; }
  }
  __syncthreads();
  if (t < NE) { count[t] = cnt[t]; start[t] = offs[t]; }
  int pos = atomicAdd(&cur[e], 1);
  list[pos] = t;
}

static __device__ __forceinline__ float4 f4ma(float a, float4 w, float4 c) {
  c.x = fmaf(a, w.x, c.x);
  c.y = fmaf(a, w.y, c.y);
  c.z = fmaf(a, w.z, c.z);
  c.w = fmaf(a, w.w, c.w);
  return c;
}

// ---------------- fused 2-layer expert MLP ----------------
// grid: (4 r-chunks, 64 experts), 256 threads = 4 waves, ~1 block/CU.
// Weights: global->LDS once per CU (async DMA, width 16, double-buffered).
// Wave (rh, sh): rh = row-half of each 32-row tile, sh = slot-half.
// Weight LDS reads duplicated only 2x (vs 4x before); slot loops bounded by
// the ACTUAL count m (uniform scalar guards -> no padding FMA).
// Per-layer cross-rh reduction goes through xs (dead x/h space).
__global__ __launch_bounds__(256) void mlp_kernel(
    const float* __restrict__ slots, const float* __restrict__ w1,
    const float* __restrict__ b1, const float* __restrict__ w2,
    const float* __restrict__ b2, const int* __restrict__ count,
    const int* __restrict__ start, const int* __restrict__ list,
    float* __restrict__ out) {
  const int rc = blockIdx.x;   // 0..3
  const int e  = blockIdx.y;   // 0..63
  const int n  = count[e];
  if (n == 0) return;
  const int t  = threadIdx.x;
  const int g4 = t & 63;       // lane's 4-column group
  const int w  = t >> 6;       // wave 0..3
  const int rh = w & 1;        // row-half within each tile
  const int sh = w >> 1;       // slot-half
  const int rbase = rc * RC;

  __shared__ float xs[TILE][DIMC];   // x tile (L1), then h tile (L2), also
                                     // reduction scratch at layer boundaries
  __shared__ float wt[2][DT][DIMC];  // double-buffered staged weight tiles
  __shared__ int   sid[TILE];

  const float* w1e = w1 + (size_t)e * DIMC * RTOT + rbase + g4 * 4;   // + d*RTOT
  const float* w2e = w2 + ((size_t)e * RTOT + rbase) * DIMC + g4 * 4; // + r*DIMC

  const float4 zero4 = make_float4(0.f, 0.f, 0.f, 0.f);
  const float4 b1v = (rh == 0) ? *(const float4*)&b1[e * RTOT + rbase + g4 * 4] : zero4;
  const float4 b2v = (rh == 0 && rc == 0) ? *(const float4*)&b2[e * DIMC + g4 * 4] : zero4;
  const int st = start[e];

  for (int s0 = 0; s0 < n; s0 += TILE) {
    const int m   = (n - s0 < TILE) ? (n - s0) : TILE;
    const int mh0 = (m + 1) >> 1;                 // slots in half 0
    const int sbase = sh * mh0;                   // my half's first slot
    const int mh  = sh ? (m - mh0) : mh0;         // my half's slot count

    __syncthreads();  // prior pass fully done before overwriting sid/xs
    if (t < m) sid[t] = list[st + s0 + t];
    __syncthreads();

    // stage w1 tile 0 (async DMA) ...
#pragma unroll
    for (int j = 0; j < DT / 4; ++j) {
      int row = w * (DT / 4) + j;
      __builtin_amdgcn_global_load_lds((gptr_t)(w1e + (size_t)row * RTOT),
                                       (lptr_t)&wt[0][row][0], 16, 0, 0);
    }
    // ... while loading the x tile (only m slots)
    for (int i = t; i < m * (DIMC / 4); i += 256) {
      int s = i >> 6, d4 = i & 63;
      *(float4*)&xs[s][d4 * 4] =
          ((const float4*)slots)[(size_t)sid[s] * (DIMC / 4) + d4];
    }
    __syncthreads();  // drains x loads + tile-0 DMA

    float4 acc[HMAX];
#pragma unroll
    for (int s = 0; s < HMAX; ++s) acc[s] = b1v;

    for (int k = 0; k < NT; ++k) {
      const int buf = k & 1;

      if (k == 8) {
        // ---- L1 -> L2 boundary: cross-rh reduction, bias+relu, h into xs.
        // x is dead; xs[s][cols] is reused as partial buffer then h buffer.
        if (rh == 1) {
#pragma unroll
          for (int s = 0; s < HMAX; ++s)
            if (s < mh) *(float4*)&xs[sbase + s][g4 * 4] = acc[s];
        }
        __syncthreads();
        if (rh == 0) {
#pragma unroll
          for (int s = 0; s < HMAX; ++s)
            if (s < mh) {
              float4 p = *(const float4*)&xs[sbase + s][g4 * 4];
              float4 h;
              h.x = fmaxf(acc[s].x + p.x, 0.f);
              h.y = fmaxf(acc[s].y + p.y, 0.f);
              h.z = fmaxf(acc[s].z + p.z, 0.f);
              h.w = fmaxf(acc[s].w + p.w, 0.f);
              *(float4*)&xs[sbase + s][g4 * 4] = h;
            }
        }
        __syncthreads();
#pragma unroll
        for (int s = 0; s < HMAX; ++s) acc[s] = b2v;
      }

      // issue next tile's DMA into the other buffer (overlaps this compute)
      if (k + 1 < NT) {
        const int kn = k + 1;
        const float* src = (kn < 8) ? (w1e + (size_t)(kn * DT) * RTOT)
                                    : (w2e + (size_t)((kn - 8) * DT) * DIMC);
        const size_t rstride = (kn < 8) ? RTOT : DIMC;
#pragma unroll
        for (int j = 0; j < DT / 4; ++j) {
          int row = w * (DT / 4) + j;
          __builtin_amdgcn_global_load_lds((gptr_t)(src + (size_t)row * rstride),
                                           (lptr_t)&wt[buf ^ 1][row][0], 16, 0, 0);
        }
      }

      // ---- compute my row-half of tile k for my slot-half
      const int xoff = ((k < 8) ? k : (k - 8)) * DT + rh * 16;
#pragma unroll
      for (int dg = 0; dg < 4; ++dg) {
        const int row = rh * 16 + dg * 4;
        float4 wA = *(const float4*)&wt[buf][row + 0][g4 * 4];
        float4 wB = *(const float4*)&wt[buf][row + 1][g4 * 4];
        float4 wC = *(const float4*)&wt[buf][row + 2][g4 * 4];
        float4 wD = *(const float4*)&wt[buf][row + 3][g4 * 4];
#pragma unroll
        for (int s = 0; s < HMAX; ++s)
          if (s < mh) {  // wave-uniform guard: scalar-branch skip, acc stays in VGPRs
            float4 xv = *(const float4*)&xs[sbase + s][xoff + dg * 4];  // broadcast
            acc[s] = f4ma(xv.x, wA, acc[s]);
            acc[s] = f4ma(xv.y, wB, acc[s]);
            acc[s] = f4ma(xv.z, wC, acc[s]);
            acc[s] = f4ma(xv.w, wD, acc[s]);
          }
      }
      __syncthreads();  // tile k consumed by all waves; next DMA drained
    }

    // ---- epilogue: cross-rh reduction of output partials, then atomics
    if (rh == 1) {
#pragma unroll
      for (int s = 0; s < HMAX; ++s)
        if (s < mh) *(float4*)&xs[sbase + s][g4 * 4] = acc[s];
    }
    __syncthreads();
    if (rh == 0) {
#pragma unroll
      for (int s = 0; s < HMAX; ++s)
        if (s < mh) {
          float4 p = *(const float4*)&xs[sbase + s][g4 * 4];
          float* po = &out[(size_t)sid[sbase + s] * DIMC + g4 * 4];
          atomicAdd(po + 0, acc[s].x + p.x);
          atomicAdd(po + 1, acc[s].y + p.y);
          atomicAdd(po + 2, acc[s].z + p.z);
          atomicAdd(po + 3, acc[s].w + p.w);
        }
    }
  }
}

extern "C" void kernel_launch(void* const* d_in, const int* in_sizes, int n_in,
                              void* d_out, int out_size, void* d_ws, size_t ws_size,
                              hipStream_t stream) {
  const float* slots   = (const float*)d_in[0];
  const float* w1      = (const float*)d_in[1];
  const float* b1      = (const float*)d_in[2];
  const float* w2      = (const float*)d_in[3];
  const float* b2      = (const float*)d_in[4];
  const int*   indices = (const int*)d_in[5];
  float* out = (float*)d_out;

  int* ws    = (int*)d_ws;
  int* count = ws;         // 64
  int* start = ws + 64;    // 64
  int* list  = ws + 128;   // 1024

  hipMemsetAsync(d_out, 0, (size_t)out_size * sizeof(float), stream);
  bucket_kernel<<<1, NSLOT, 0, stream>>>(indices, count, start, list);
  mlp_kernel<<<dim3(4, NE), 256, 0, stream>>>(slots, w1, b1, w2, b2,
                                              count, start, list, out);
}

// Round 6
// 179.373 us; speedup vs baseline: 1.1311x; 1.1311x over previous
//
#include <hip/hip_runtime.h>
#include <stdint.h>

#define DIMC 256
#define RTOT 1024
#define NE 64
#define NSLOT 1024
#define RC 256     // r-columns per block (grid.x = 4)
#define TILE 32    // max slots per pass (2 MFMA m-tiles)
#define XSTR 264   // padded LDS row stride in bf16 elems (264*2=528B, 16B-aligned, bank-safe)
#define KS 8       // k-steps per layer (256 / 32)
#define NTW 4      // n-tiles per wave (4 waves x 4 x 16 = 256 cols)

typedef short bfrag __attribute__((ext_vector_type(8)));   // 8 bf16 (4 VGPRs)
typedef float f32x4 __attribute__((ext_vector_type(4)));   // MFMA accumulator

// ---------------- bucket slots by expert ----------------
__global__ __launch_bounds__(1024) void bucket_kernel(
    const int* __restrict__ idx, int* __restrict__ count,
    int* __restrict__ start, int* __restrict__ list) {
  __shared__ int cnt[NE];
  __shared__ int offs[NE];
  __shared__ int cur[NE];
  int t = threadIdx.x;
  if (t < NE) cnt[t] = 0;
  __syncthreads();
  int e = idx[t] & (NE - 1);
  atomicAdd(&cnt[e], 1);
  __syncthreads();
  if (t == 0) {
    int acc = 0;
    for (int i = 0; i < NE; ++i) { offs[i] = acc; cur[i] = acc; acc += cnt[i]; }
  }
  __syncthreads();
  if (t < NE) { count[t] = cnt[t]; start[t] = offs[t]; }
  int pos = atomicAdd(&cur[e], 1);
  list[pos] = t;
}

static __device__ __forceinline__ unsigned short f2bf(float f) {
  unsigned u = __float_as_uint(f);            // round-to-nearest-even
  return (unsigned short)((u + 0x7FFFu + ((u >> 16) & 1u)) >> 16);
}

static __device__ __forceinline__ bfrag pack8(const float* f) {
  union { unsigned short u[8]; bfrag v; } r;
#pragma unroll
  for (int i = 0; i < 8; ++i) r.u[i] = f2bf(f[i]);
  return r.v;
}

// ---------------- fused 2-layer expert MLP via MFMA ----------------
// grid: (4 r-chunks, 64 experts), 256 threads = 4 waves, 1 block/CU.
// Per layer: D(M=32 slots, N=256) = A(32 x K=256) * B(256 x N).
// B fragments load DIRECTLY from global w1/w2 (already [k][n] row-major):
// lane l, elem j -> B[kbase + (l>>4)*8 + j][n0 + (l&15)]  (8 dwords, each
// instr = 4 coalesced 64B segments, no duplication: waves own distinct cols).
// A fragments (x, then h) from a 17 KB bf16 LDS buffer: A[m=l&15][k=(l>>4)*8+j].
// A/B use the same (lane,j)->k map, so any k-order bijection cancels.
// C/D: col=l&15, row=(l>>4)*4+reg  [m89-verified].
__global__ __launch_bounds__(256) void mlp_kernel(
    const float* __restrict__ slots, const float* __restrict__ w1,
    const float* __restrict__ b1, const float* __restrict__ w2,
    const float* __restrict__ b2, const int* __restrict__ count,
    const int* __restrict__ start, const int* __restrict__ list,
    float* __restrict__ out) {
  const int rc = blockIdx.x;   // 0..3
  const int e  = blockIdx.y;   // 0..63
  const int n  = count[e];
  if (n == 0) return;
  const int t  = threadIdx.x;
  const int l  = t & 63;       // lane
  const int w  = t >> 6;       // wave 0..3
  const int ln = l & 15;       // fragment n/m index
  const int kg = l >> 4;       // k-group 0..3
  const int rbase = rc * RC;
  const int n0 = w * 64;       // wave's 64-column window
  const int st = start[e];

  __shared__ unsigned short X[TILE * XSTR];  // bf16 A-operand: x (L1), h (L2)
  __shared__ int sid[TILE];

  const float* w1e = w1 + (size_t)e * DIMC * RTOT + rbase;             // [d][r]
  const float* w2e = w2 + (size_t)e * RTOT * DIMC + (size_t)rbase * DIMC; // [r][dout]

  for (int s0 = 0; s0 < n; s0 += TILE) {
    const int m = (n - s0 < TILE) ? (n - s0) : TILE;

    __syncthreads();  // prior pass fully done
    if (t < TILE) sid[t] = (t < m) ? list[st + s0 + t] : 0;
    __syncthreads();

    // ---- stage x tile: fp32 global -> bf16 LDS [slot][d]; zero pad rows
    for (int i = t; i < TILE * 64; i += 256) {
      int s = i >> 6, d4 = (i & 63) * 4;
      float4 v = make_float4(0.f, 0.f, 0.f, 0.f);
      if (s < m) v = ((const float4*)slots)[(size_t)sid[s] * 64 + (i & 63)];
      union { unsigned short u[4]; uint2 q; } p;
      p.u[0] = f2bf(v.x); p.u[1] = f2bf(v.y);
      p.u[2] = f2bf(v.z); p.u[3] = f2bf(v.w);
      *(uint2*)&X[s * XSTR + d4] = p.q;
    }
    __syncthreads();

    f32x4 acc[2][NTW];
#pragma unroll
    for (int mt = 0; mt < 2; ++mt)
#pragma unroll
      for (int nt = 0; nt < NTW; ++nt) acc[mt][nt] = (f32x4)(0.f);

    // ================= layer 1: h = x @ w1 =================
    {
      float bc[NTW][8], bn[NTW][8];
#pragma unroll
      for (int nt = 0; nt < NTW; ++nt)
#pragma unroll
        for (int j = 0; j < 8; ++j)
          bc[nt][j] = w1e[(size_t)(kg * 8 + j) * RTOT + n0 + nt * 16 + ln];

#pragma unroll
      for (int ks = 0; ks < KS; ++ks) {
        if (ks + 1 < KS) {
          const int kb = (ks + 1) * 32;
#pragma unroll
          for (int nt = 0; nt < NTW; ++nt)
#pragma unroll
            for (int j = 0; j < 8; ++j)
              bn[nt][j] = w1e[(size_t)(kb + kg * 8 + j) * RTOT + n0 + nt * 16 + ln];
        }
        const unsigned short* xp = &X[(size_t)ln * XSTR + ks * 32 + kg * 8];
        bfrag a0 = *(const bfrag*)xp;
        bfrag a1 = *(const bfrag*)(xp + 16 * XSTR);
#pragma unroll
        for (int nt = 0; nt < NTW; ++nt) {
          bfrag b = pack8(bc[nt]);
          acc[0][nt] = __builtin_amdgcn_mfma_f32_16x16x32_bf16(a0, b, acc[0][nt], 0, 0, 0);
          acc[1][nt] = __builtin_amdgcn_mfma_f32_16x16x32_bf16(a1, b, acc[1][nt], 0, 0, 0);
        }
#pragma unroll
        for (int nt = 0; nt < NTW; ++nt)
#pragma unroll
          for (int j = 0; j < 8; ++j) bc[nt][j] = bn[nt][j];
      }
    }

    __syncthreads();  // all waves done reading x from X

    // ---- bias + relu, park h (bf16) into X[m][r]; C row = kg*4+reg
#pragma unroll
    for (int nt = 0; nt < NTW; ++nt) {
      const int col = n0 + nt * 16 + ln;
      const float b1v = b1[e * RTOT + rbase + col];
#pragma unroll
      for (int mt = 0; mt < 2; ++mt) {
#pragma unroll
        for (int reg = 0; reg < 4; ++reg) {
          float h = fmaxf(acc[mt][nt][reg] + b1v, 0.f);
          X[(mt * 16 + kg * 4 + reg) * XSTR + col] = f2bf(h);
        }
        acc[mt][nt] = (f32x4)(0.f);
      }
    }
    __syncthreads();

    // ================= layer 2: out = h @ w2 =================
    {
      float bc[NTW][8], bn[NTW][8];
#pragma unroll
      for (int nt = 0; nt < NTW; ++nt)
#pragma unroll
        for (int j = 0; j < 8; ++j)
          bc[nt][j] = w2e[(size_t)(kg * 8 + j) * DIMC + n0 + nt * 16 + ln];

#pragma unroll
      for (int ks = 0; ks < KS; ++ks) {
        if (ks + 1 < KS) {
          const int kb = (ks + 1) * 32;
#pragma unroll
          for (int nt = 0; nt < NTW; ++nt)
#pragma unroll
            for (int j = 0; j < 8; ++j)
              bn[nt][j] = w2e[(size_t)(kb + kg * 8 + j) * DIMC + n0 + nt * 16 + ln];
        }
        const unsigned short* xp = &X[(size_t)ln * XSTR + ks * 32 + kg * 8];
        bfrag a0 = *(const bfrag*)xp;
        bfrag a1 = *(const bfrag*)(xp + 16 * XSTR);
#pragma unroll
        for (int nt = 0; nt < NTW; ++nt) {
          bfrag b = pack8(bc[nt]);
          acc[0][nt] = __builtin_amdgcn_mfma_f32_16x16x32_bf16(a0, b, acc[0][nt], 0, 0, 0);
          acc[1][nt] = __builtin_amdgcn_mfma_f32_16x16x32_bf16(a1, b, acc[1][nt], 0, 0, 0);
        }
#pragma unroll
        for (int nt = 0; nt < NTW; ++nt)
#pragma unroll
          for (int j = 0; j < 8; ++j) bc[nt][j] = bn[nt][j];
      }
    }

    // ---- epilogue: out[sid[row]][col] += acc (+ b2 once, via rc==0 block)
#pragma unroll
    for (int nt = 0; nt < NTW; ++nt) {
      const int col = n0 + nt * 16 + ln;
      const float b2v = (rc == 0) ? b2[e * DIMC + col] : 0.f;
#pragma unroll
      for (int mt = 0; mt < 2; ++mt)
#pragma unroll
        for (int reg = 0; reg < 4; ++reg) {
          const int row = mt * 16 + kg * 4 + reg;
          if (row < m)
            atomicAdd(&out[(size_t)sid[row] * DIMC + col], acc[mt][nt][reg] + b2v);
        }
    }
  }
}

extern "C" void kernel_launch(void* const* d_in, const int* in_sizes, int n_in,
                              void* d_out, int out_size, void* d_ws, size_t ws_size,
                              hipStream_t stream) {
  const float* slots   = (const float*)d_in[0];
  const float* w1      = (const float*)d_in[1];
  const float* b1      = (const float*)d_in[2];
  const float* w2      = (const float*)d_in[3];
  const float* b2      = (const float*)d_in[4];
  const int*   indices = (const int*)d_in[5];
  float* out = (float*)d_out;

  int* ws    = (int*)d_ws;
  int* count = ws;         // 64
  int* start = ws + 64;    // 64
  int* list  = ws + 128;   // 1024

  hipMemsetAsync(d_out, 0, (size_t)out_size * sizeof(float), stream);
  bucket_kernel<<<1, NSLOT, 0, stream>>>(indices, count, start, list);
  mlp_kernel<<<dim3(4, NE), 256, 0, stream>>>(slots, w1, b1, w2, b2,
                                              count, start, list, out);
}

// Round 7
// 171.391 us; speedup vs baseline: 1.1838x; 1.0466x over previous
//
#include <hip/hip_runtime.h>
#include <stdint.h>

#define DIMC 256
#define RTOT 1024
#define NE 64
#define NSLOT 1024
#define RCN 8      // r-chunks (grid.x)
#define RCW 128    // r-columns per chunk
#define TILE 32    // max slots per pass (2 MFMA m-tiles)
#define XSTR 264   // padded LDS row stride (bf16 elems)
#define KS1 8      // L1 k-steps (256/32)
#define KS2 4      // L2 k-steps (128/32)
#define NTW2 2     // L2 n-tiles per wave (8 waves x 2 x 16 = 256)

typedef short bfrag __attribute__((ext_vector_type(8)));
typedef float f32x4 __attribute__((ext_vector_type(4)));

// ---------------- bucket slots by expert ----------------
__global__ __launch_bounds__(1024) void bucket_kernel(
    const int* __restrict__ idx, int* __restrict__ count,
    int* __restrict__ start, int* __restrict__ list) {
  __shared__ int cnt[NE];
  __shared__ int offs[NE];
  __shared__ int cur[NE];
  int t = threadIdx.x;
  if (t < NE) cnt[t] = 0;
  __syncthreads();
  int e = idx[t] & (NE - 1);
  atomicAdd(&cnt[e], 1);
  __syncthreads();
  if (t == 0) {
    int acc = 0;
    for (int i = 0; i < NE; ++i) { offs[i] = acc; cur[i] = acc; acc += cnt[i]; }
  }
  __syncthreads();
  if (t < NE) { count[t] = cnt[t]; start[t] = offs[t]; }
  int pos = atomicAdd(&cur[e], 1);
  list[pos] = t;
}

static __device__ __forceinline__ unsigned short f2bf(float f) {
  unsigned u = __float_as_uint(f);  // RNE
  return (unsigned short)((u + 0x7FFFu + ((u >> 16) & 1u)) >> 16);
}

static __device__ __forceinline__ bfrag pack8(const float* f) {
  union { unsigned short u[8]; bfrag v; } r;
#pragma unroll
  for (int i = 0; i < 8; ++i) r.u[i] = f2bf(f[i]);
  return r.v;
}

// ---------------- fused 2-layer expert MLP via MFMA ----------------
// grid: (8 r-chunks, 64 experts), 512 threads = 8 waves, 2 blocks/CU.
// Each block owns a DISJOINT 128-col chunk of w1[e] and 128-row chunk of
// w2[e]: total device weight traffic stays compulsory (128 MB) while TLP
// quadruples vs R6 (16 waves/CU) to raise memory-level parallelism.
// B-fragments load directly from global [k][n] (8 strided dwords/lane,
// each instr = 4 coalesced 64B segments). A (x, then h) from bf16 LDS.
// C/D: col=lane&15, row=(lane>>4)*4+reg.
__global__ __launch_bounds__(512) void mlp_kernel(
    const float* __restrict__ slots, const float* __restrict__ w1,
    const float* __restrict__ b1, const float* __restrict__ w2,
    const float* __restrict__ b2, const int* __restrict__ count,
    const int* __restrict__ start, const int* __restrict__ list,
    float* __restrict__ out) {
  const int rc = blockIdx.x;   // 0..7
  const int e  = blockIdx.y;   // 0..63
  const int n  = count[e];
  if (n == 0) return;
  const int t  = threadIdx.x;
  const int l  = t & 63;       // lane
  const int w  = t >> 6;       // wave 0..7
  const int ln = l & 15;       // fragment n/m index
  const int kg = l >> 4;       // k-group 0..3
  const int rbase = rc * RCW;
  const int st = start[e];

  __shared__ unsigned short X[TILE * XSTR];  // bf16 A-operand: x (L1), h (L2)
  __shared__ int sid[TILE];

  const float* w1e = w1 + (size_t)e * DIMC * RTOT + rbase;                // [d][r]
  const float* w2e = w2 + (size_t)e * RTOT * DIMC + (size_t)rbase * DIMC; // [r][dout]

  for (int s0 = 0; s0 < n; s0 += TILE) {
    const int m = (n - s0 < TILE) ? (n - s0) : TILE;

    __syncthreads();
    if (t < TILE) sid[t] = (t < m) ? list[st + s0 + t] : 0;
    __syncthreads();

    // ---- stage x tile: fp32 global -> bf16 LDS [slot][d]; zero pad rows
    for (int i = t; i < TILE * 64; i += 512) {
      int s = i >> 6, d4 = (i & 63) * 4;
      float4 v = make_float4(0.f, 0.f, 0.f, 0.f);
      if (s < m) v = ((const float4*)slots)[(size_t)sid[s] * 64 + (i & 63)];
      union { unsigned short u[4]; uint2 q; } p;
      p.u[0] = f2bf(v.x); p.u[1] = f2bf(v.y);
      p.u[2] = f2bf(v.z); p.u[3] = f2bf(v.w);
      *(uint2*)&X[s * XSTR + d4] = p.q;
    }
    __syncthreads();

    // ================= layer 1: h = x @ w1 chunk (N=128, K=256) =========
    // wave w owns local cols w*16 .. w*16+15 (NTW=1)
    f32x4 acc1[2];
    acc1[0] = (f32x4)(0.f); acc1[1] = (f32x4)(0.f);
    {
      const int col = w * 16 + ln;  // local r
      float bc[8], bn[8];
#pragma unroll
      for (int j = 0; j < 8; ++j)
        bc[j] = w1e[(size_t)(kg * 8 + j) * RTOT + col];

#pragma unroll
      for (int ks = 0; ks < KS1; ++ks) {
        if (ks + 1 < KS1) {
          const int kb = (ks + 1) * 32;
#pragma unroll
          for (int j = 0; j < 8; ++j)
            bn[j] = w1e[(size_t)(kb + kg * 8 + j) * RTOT + col];
        }
        const unsigned short* xp = &X[(size_t)ln * XSTR + ks * 32 + kg * 8];
        bfrag a0 = *(const bfrag*)xp;
        bfrag a1 = *(const bfrag*)(xp + 16 * XSTR);
        bfrag b = pack8(bc);
        acc1[0] = __builtin_amdgcn_mfma_f32_16x16x32_bf16(a0, b, acc1[0], 0, 0, 0);
        acc1[1] = __builtin_amdgcn_mfma_f32_16x16x32_bf16(a1, b, acc1[1], 0, 0, 0);
#pragma unroll
        for (int j = 0; j < 8; ++j) bc[j] = bn[j];
      }
    }

    __syncthreads();  // all waves done reading x from X

    // ---- bias + relu, park h (bf16) into X[m][r_local]
    {
      const int col = w * 16 + ln;
      const float b1v = b1[e * RTOT + rbase + col];
#pragma unroll
      for (int mt = 0; mt < 2; ++mt)
#pragma unroll
        for (int reg = 0; reg < 4; ++reg) {
          float h = fmaxf(acc1[mt][reg] + b1v, 0.f);
          X[(mt * 16 + kg * 4 + reg) * XSTR + col] = f2bf(h);
        }
    }
    __syncthreads();

    // ================= layer 2: out += h @ w2 chunk (N=256, K=128) ======
    // wave w owns output cols w*32 .. w*32+31 (NTW2=2)
    f32x4 acc2[2][NTW2];
#pragma unroll
    for (int mt = 0; mt < 2; ++mt)
#pragma unroll
      for (int nt = 0; nt < NTW2; ++nt) acc2[mt][nt] = (f32x4)(0.f);
    {
      float bc[NTW2][8], bn[NTW2][8];
#pragma unroll
      for (int nt = 0; nt < NTW2; ++nt)
#pragma unroll
        for (int j = 0; j < 8; ++j)
          bc[nt][j] = w2e[(size_t)(kg * 8 + j) * DIMC + w * 32 + nt * 16 + ln];

#pragma unroll
      for (int ks = 0; ks < KS2; ++ks) {
        if (ks + 1 < KS2) {
          const int kb = (ks + 1) * 32;
#pragma unroll
          for (int nt = 0; nt < NTW2; ++nt)
#pragma unroll
            for (int j = 0; j < 8; ++j)
              bn[nt][j] = w2e[(size_t)(kb + kg * 8 + j) * DIMC + w * 32 + nt * 16 + ln];
        }
        const unsigned short* xp = &X[(size_t)ln * XSTR + ks * 32 + kg * 8];
        bfrag a0 = *(const bfrag*)xp;
        bfrag a1 = *(const bfrag*)(xp + 16 * XSTR);
#pragma unroll
        for (int nt = 0; nt < NTW2; ++nt) {
          bfrag b = pack8(bc[nt]);
          acc2[0][nt] = __builtin_amdgcn_mfma_f32_16x16x32_bf16(a0, b, acc2[0][nt], 0, 0, 0);
          acc2[1][nt] = __builtin_amdgcn_mfma_f32_16x16x32_bf16(a1, b, acc2[1][nt], 0, 0, 0);
        }
#pragma unroll
        for (int nt = 0; nt < NTW2; ++nt)
#pragma unroll
          for (int j = 0; j < 8; ++j) bc[nt][j] = bn[nt][j];
      }
    }

    // ---- epilogue: out[sid[row]][col] += acc (+ b2 once via rc==0)
#pragma unroll
    for (int nt = 0; nt < NTW2; ++nt) {
      const int col = w * 32 + nt * 16 + ln;
      const float b2v = (rc == 0) ? b2[e * DIMC + col] : 0.f;
#pragma unroll
      for (int mt = 0; mt < 2; ++mt)
#pragma unroll
        for (int reg = 0; reg < 4; ++reg) {
          const int row = mt * 16 + kg * 4 + reg;
          if (row < m)
            atomicAdd(&out[(size_t)sid[row] * DIMC + col], acc2[mt][nt][reg] + b2v);
        }
    }
  }
}

extern "C" void kernel_launch(void* const* d_in, const int* in_sizes, int n_in,
                              void* d_out, int out_size, void* d_ws, size_t ws_size,
                              hipStream_t stream) {
  const float* slots   = (const float*)d_in[0];
  const float* w1      = (const float*)d_in[1];
  const float* b1      = (const float*)d_in[2];
  const float* w2      = (const float*)d_in[3];
  const float* b2      = (const float*)d_in[4];
  const int*   indices = (const int*)d_in[5];
  float* out = (float*)d_out;

  int* ws    = (int*)d_ws;
  int* count = ws;         // 64
  int* start = ws + 64;    // 64
  int* list  = ws + 128;   // 1024

  hipMemsetAsync(d_out, 0, (size_t)out_size * sizeof(float), stream);
  bucket_kernel<<<1, NSLOT, 0, stream>>>(indices, count, start, list);
  mlp_kernel<<<dim3(RCN, NE), 512, 0, stream>>>(slots, w1, b1, w2, b2,
                                                count, start, list, out);
}